// Round 20
// baseline (2487.476 us; speedup 1.0000x reference)
//
#include <hip/hip_runtime.h>
#include <stdint.h>

#define B_  256
#define S_  512
#define D_  64
#define H_  256
#define G3_ 768

typedef __attribute__((ext_vector_type(8))) short s8v;   // 8 bf16 (4 VGPRs)
typedef __attribute__((ext_vector_type(4))) short s4v;   // 4 bf16 (2 VGPRs)
typedef __attribute__((ext_vector_type(4))) float f4v;   // MFMA accumulator
typedef __attribute__((ext_vector_type(4))) float f4r;   // raw float4

#define MF(a, b, c) __builtin_amdgcn_mfma_f32_16x16x32_bf16((a), (b), (c), 0, 0, 0)

__device__ __forceinline__ unsigned short f2bf(float x) {  // RNE
  unsigned u = __float_as_uint(x);
  unsigned r = (u + 0x7fffu + ((u >> 16) & 1u)) >> 16;
  return (unsigned short)r;
}
__device__ __forceinline__ float bf2f(unsigned short s) {
  return __uint_as_float(((unsigned)s) << 16);
}
__device__ __forceinline__ float sigm(float x) {
  return __builtin_amdgcn_rcpf(1.f + __expf(-x));
}
__device__ __forceinline__ float tanh_f(float x) {
  return 1.f - 2.f * __builtin_amdgcn_rcpf(1.f + __expf(2.f * x));
}

__device__ __forceinline__ void waitFlag(unsigned* p, unsigned target) {
  while (__hip_atomic_load(p, __ATOMIC_RELAXED, __HIP_MEMORY_SCOPE_AGENT) < target)
    __builtin_amdgcn_s_sleep(2);
  (void)__hip_atomic_load(p, __ATOMIC_ACQUIRE, __HIP_MEMORY_SCOPE_AGENT);
}
__device__ __forceinline__ void postFlag(unsigned* p) {
  __threadfence();   // agent release: L2 writeback of this XCD's dirty lines
  __hip_atomic_fetch_add(p, 1u, __ATOMIC_RELEASE, __HIP_MEMORY_SCOPE_AGENT);
}

// ---------------------------------------------------------------------------
// Generic fp32 -> bf16 pack (8 elements/thread).
// ---------------------------------------------------------------------------
__global__ __launch_bounds__(256) void pack_bf16(
    const float* __restrict__ src, unsigned short* __restrict__ dst, int n8)
{
  const int i = blockIdx.x * 256 + threadIdx.x;
  if (i >= n8) return;
  const float4 f0 = *(const float4*)(src + (size_t)i * 8);
  const float4 f1 = *(const float4*)(src + (size_t)i * 8 + 4);
  unsigned short h[8] = { f2bf(f0.x), f2bf(f0.y), f2bf(f0.z), f2bf(f0.w),
                          f2bf(f1.x), f2bf(f1.y), f2bf(f1.z), f2bf(f1.w) };
  *(s8v*)&dst[(size_t)i * 8] = *(s8v*)h;
}

// ---------------------------------------------------------------------------
// Pack W_hh into MFMA fragment order (bf16-hi) + fold biases (block 0,0).
// ---------------------------------------------------------------------------
__global__ __launch_bounds__(64) void pack_whh(
    const float* __restrict__ Whh, unsigned short* __restrict__ Whp,
    const float* __restrict__ bih, const float* __restrict__ bhh,
    float* __restrict__ bias2)
{
  const int gti = blockIdx.x, kc = blockIdx.y, lane = threadIdx.x;
  const int rowp = gti * 16 + (lane & 15);
  const int k0  = kc * 32 + (lane >> 4) * 8;
  const float* src = &Whh[(size_t)rowp * H_ + k0];
  unsigned short hi8[8];
  #pragma unroll
  for (int s = 0; s < 8; ++s) hi8[s] = f2bf(src[s]);
  const size_t o = ((size_t)(gti * 8 + kc) * 64 + lane) * 8;
  *(s8v*)&Whp[o] = *(s8v*)hi8;

  if (gti == 0 && kc == 0) {
    #pragma unroll
    for (int i = 0; i < 12; ++i) {
      int g = i * 64 + lane;
      bias2[g] = bih[g] + (g < 512 ? bhh[g] : 0.f);
    }
  }
}

// ---------------------------------------------------------------------------
// Persistent cooperative pipeline. 256 co-resident blocks:
//   [0,48): scan WGs — block b: layer l=b/16, batch group b%16. W loaded ONCE;
//     h in registers across ALL chunks. Per chunk c: wait gemm_done[l][c],
//     run CH steps, release scan_done[l][c].
//   [48,256): gemm workers — static tile = wkr (< CH*12). Iterate chunks in
//     slot order s=c+2l; deps: scan_done[l-1][c] (ybf RAW), scan_done[l][c-2]
//     (gx WAR). Compute tile, release gemm_done[l][c].
// DAG is slot-ordered -> deadlock-free. Cross-XCD visibility: __threadfence
// (L2 wb) before release-add; acquire-load (L1/L2 inv) before reads.
// ---------------------------------------------------------------------------
__global__ __launch_bounds__(1024, 4) void persist_k(
    int CH, int chsh, int cpl,
    const float* __restrict__ x, unsigned short* __restrict__ ybf,
    const unsigned short* __restrict__ wihp,
    const unsigned short* __restrict__ Whp, const float* __restrict__ bhh_all,
    const float* __restrict__ bias2, unsigned short* __restrict__ gxbase,
    float* __restrict__ hbuf, unsigned* __restrict__ gemm_done,
    unsigned* __restrict__ scan_done)
{
  const int tid = threadIdx.x;
  const int wid = tid >> 6, lane = tid & 63;
  const int fr = lane & 15, fq = lane >> 4;
  const size_t gx_elems = (size_t)B_ * CH * G3_;
  const unsigned NTILES = (unsigned)(CH * 12);

  extern __shared__ unsigned short lds_[];

  if (blockIdx.x < 48) {
    // ===================== SCAN ROLE (persistent) ==========================
    const int l = blockIdx.x >> 4;

    const unsigned short* Whp_s = Whp + (size_t)l * G3_ * H_;
    const float* bhh_s = bhh_all + (size_t)l * G3_;
    float* hb = hbuf + (size_t)l * B_ * H_;
    const int lastL = (l == 2) ? 1 : 0;

    unsigned short* WhN  = lds_;                 // [16 w][8 kc][512] = 128KB
    unsigned short* Abuf = lds_ + 65536;         // [2][8 kc][512] = 16KB

    const int bid = blockIdx.x & 15;
    const int b0  = bid * 16;
    const int bb  = fr;

    const s8v* WhpV = (const s8v*)Whp_s;

    s8v whr[8], whz[8];
    #pragma unroll
    for (int kc = 0; kc < 8; ++kc) {
      whr[kc] = WhpV[((     wid) * 8 + kc) * 64 + lane];
      whz[kc] = WhpV[((16 + wid) * 8 + kc) * 64 + lane];
    }
    #pragma unroll
    for (int kc = 0; kc < 8; ++kc) {
      s8v v = WhpV[((32 + wid) * 8 + kc) * 64 + lane];
      *(s8v*)&WhN[(wid * 8 + kc) * 512 + lane * 8] = v;
    }

    const int u0 = 16 * wid + 4 * fq;
    const f4r bhn4 = *(const f4r*)&bhh_s[2 * H_ + u0];

    f4r hn4 = {0.f, 0.f, 0.f, 0.f};       // full sequence starts at h=0

    const int kcw  = wid >> 1;
    const int lp   = bb | (((2 * wid + (fq >> 1)) & 3) << 4);
    const int eo   = (fq & 1) * 4;
    const int aoff = kcw * 512 + lp * 8 + eo;

    {
      s4v hh;
      #pragma unroll
      for (int j = 0; j < 4; ++j) hh[j] = (short)f2bf(hn4[j]);
      *(s4v*)&Abuf[aoff] = hh;
    }

    int cur = 0;
    for (int c = 0; c < cpl; ++c) {
      if (tid == 0) waitFlag(&gemm_done[l * cpl + c], NTILES);
      __syncthreads();   // all threads see acquire; Abuf state also synced

      const unsigned short* gx_r = gxbase + (size_t)(2 * l + (c & 1)) * gx_elems;
      const int t0s = c * CH;

      // preload gx(t=0), bf16
      const unsigned short* gb0 = gx_r + ((size_t)(b0 + bb) * CH) * G3_;
      s4v xr4 = *(const s4v*)(gb0 + u0);
      s4v xz4 = *(const s4v*)(gb0 + H_ + u0);
      s4v xn4 = *(const s4v*)(gb0 + 2 * H_ + u0);

      for (int t = 0; t < CH; ++t) {
        __syncthreads();   // Abuf[cur] visible

        const int tn = (t + 1 < CH) ? t + 1 : t;
        const unsigned short* gbn = gx_r + ((size_t)(b0 + bb) * CH + tn) * G3_;
        s4v xr_n = *(const s4v*)(gbn + u0);
        s4v xz_n = *(const s4v*)(gbn + H_ + u0);
        s4v xn_n = *(const s4v*)(gbn + 2 * H_ + u0);

        f4v accR = {}, accZ = {}, accN = {};
        #pragma unroll
        for (int kc = 0; kc < 8; ++kc) {
          s8v ahh = *(const s8v*)&Abuf[cur * 4096 + kc * 512 + lane * 8];
          s8v wn  = *(const s8v*)&WhN[(wid * 8 + kc) * 512 + lane * 8];
          accR = MF(whr[kc], ahh, accR);
          accZ = MF(whz[kc], ahh, accZ);
          accN = MF(wn,      ahh, accN);
        }

        #pragma unroll
        for (int i = 0; i < 4; ++i) {
          const float r = sigm(bf2f((unsigned short)xr4[i]) + accR[i]);
          const float z = sigm(bf2f((unsigned short)xz4[i]) + accZ[i]);
          const float n = tanh_f(bf2f((unsigned short)xn4[i]) + r * (accN[i] + bhn4[i]));
          hn4[i] = (1.f - z) * n + z * hn4[i];
        }
        s4v hh;
        #pragma unroll
        for (int j = 0; j < 4; ++j) hh[j] = (short)f2bf(hn4[j]);
        if (!lastL) {
          *(s4v*)&ybf[((size_t)(b0 + bb) * S_ + (t0s + t)) * H_ + u0] = hh;
        }
        *(s4v*)&Abuf[(cur ^ 1) * 4096 + aoff] = hh;
        xr4 = xr_n; xz4 = xz_n; xn4 = xn_n;
        cur ^= 1;
      }

      __syncthreads();   // all threads' stores drained (vmcnt(0) at barrier)
      if (tid == 0) postFlag(&scan_done[l * cpl + c]);
    }

    *(f4r*)&hb[(size_t)(b0 + bb) * H_ + u0] = hn4;

  } else {
    // ===================== GEMM WORKER (persistent) ========================
    const int wkr = blockIdx.x - 48;
    if (wkr >= (int)NTILES) return;      // uniform per block; no divergence

    const int mtile = wkr / 12, gtile = wkr % 12;
    const int r0 = mtile * 256, g0 = gtile * 64;

    unsigned short* Ah  = lds_;            // [256][40] = 20480 B
    unsigned short* Wh  = lds_ + 10240;    // [64][40]  = 5120 B
    unsigned short* gxs = lds_ + 12800;    // [256][72] padded = 36864 B

    const int row = tid >> 2;              // 0..255
    const int ks  = (tid & 3) * 8;

    for (int s = 0; s <= cpl + 3; ++s) {
      for (int l = 0; l < 3; ++l) {
        const int c = s - 2 * l;
        if (c < 0 || c >= cpl) continue;

        if (tid == 0) {
          if (l > 0)  waitFlag(&scan_done[(l - 1) * cpl + c], 16u);
          if (c >= 2) waitFlag(&scan_done[l * cpl + (c - 2)], 16u);
        }
        __syncthreads();

        const int    K   = (l == 0) ? D_ : H_;
        const unsigned short* Wp =
            (l == 0) ? wihp : (wihp + 49152 + (size_t)(l - 1) * 196608);
        const float* b2g = bias2 + l * 768;
        unsigned short* gx_w = gxbase + (size_t)(2 * l + (c & 1)) * gx_elems;
        const int t0g = c * CH;

        const int r = r0 + row;
        const int rg = ((r >> chsh) * S_) + t0g + (r & (CH - 1));

        f4v acc[4] = {};

        // prefetched staged K-loop
        s8v aval, wval, avalN, wvalN;
        {
          if (l == 0) {
            const float* apf = x + (size_t)rg * D_ + ks;
            float4 f0 = *(const float4*)(apf);
            float4 f1 = *(const float4*)(apf + 4);
            unsigned short a8[8] = { f2bf(f0.x), f2bf(f0.y), f2bf(f0.z), f2bf(f0.w),
                                     f2bf(f1.x), f2bf(f1.y), f2bf(f1.z), f2bf(f1.w) };
            aval = *(s8v*)a8;
          } else {
            aval = *(const s8v*)(ybf + (size_t)rg * H_ + ks);
          }
          if (tid < 256)
            wval = *(const s8v*)(Wp + (size_t)(g0 + row) * K + ks);
        }
        for (int k0 = 0; k0 < K; k0 += 32) {
          __syncthreads();   // prev frag reads done
          *(s8v*)&Ah[row * 40 + ks] = aval;
          if (tid < 256) *(s8v*)&Wh[row * 40 + ks] = wval;
          if (k0 + 32 < K) {
            const int kn = k0 + 32;
            if (l == 0) {
              const float* apf = x + (size_t)rg * D_ + kn + ks;
              float4 f0 = *(const float4*)(apf);
              float4 f1 = *(const float4*)(apf + 4);
              unsigned short a8[8] = { f2bf(f0.x), f2bf(f0.y), f2bf(f0.z), f2bf(f0.w),
                                       f2bf(f1.x), f2bf(f1.y), f2bf(f1.z), f2bf(f1.w) };
              avalN = *(s8v*)a8;
            } else {
              avalN = *(const s8v*)(ybf + (size_t)rg * H_ + kn + ks);
            }
            if (tid < 256)
              wvalN = *(const s8v*)(Wp + (size_t)(g0 + row) * K + kn + ks);
          }
          __syncthreads();

          s8v a_hi = *(const s8v*)&Ah[(16 * wid + fr) * 40 + fq * 8];
          #pragma unroll
          for (int cc = 0; cc < 4; ++cc) {
            s8v b_hi = *(const s8v*)&Wh[(cc * 16 + fr) * 40 + fq * 8];
            acc[cc] = MF(a_hi, b_hi, acc[cc]);
          }
          aval = avalN; wval = wvalN;
        }

        // epilogue: bf16 -> padded LDS bounce -> coalesced stores
        __syncthreads();   // MFMA frag reads done before gxs overwrites Ah? (gxs disjoint; barrier orders prior reads anyway)
        #pragma unroll
        for (int cc = 0; cc < 4; ++cc) {
          const float bi = b2g[g0 + cc * 16 + fr];
          #pragma unroll
          for (int i = 0; i < 4; ++i)
            gxs[(wid * 16 + fq * 4 + i) * 72 + cc * 16 + fr] = f2bf(acc[cc][i] + bi);
        }
        __syncthreads();
        {
          const int srow = tid >> 2, soff = (tid & 3) * 16;
          s8v v0 = *(const s8v*)&gxs[srow * 72 + soff];
          s8v v1 = *(const s8v*)&gxs[srow * 72 + soff + 8];
          unsigned short* gp = gx_w + (size_t)(r0 + srow) * G3_ + g0 + soff;
          *(s8v*)gp = v0;
          *(s8v*)(gp + 8) = v1;
        }

        __syncthreads();   // stores drained (vmcnt(0))
        if (tid == 0) postFlag(&gemm_done[l * cpl + c]);
      }
    }
  }
}

// ---------------------------------------------------------------------------
// Head: LayerNorm(h_last) -> MLP 256->32 (ReLU) -> 32->1. One wave per batch.
// ---------------------------------------------------------------------------
__global__ __launch_bounds__(64) void head_kernel(
    const float* __restrict__ hlast, const float* __restrict__ lng,
    const float* __restrict__ lnb, const float* __restrict__ W1,
    const float* __restrict__ b1, const float* __restrict__ W2,
    const float* __restrict__ b2, float* __restrict__ out)
{
  const int b = blockIdx.x;
  const int lane = threadIdx.x;
  float4 v = *(const float4*)&hlast[(size_t)b * H_ + lane * 4];
  float s = v.x + v.y + v.z + v.w;
  #pragma unroll
  for (int m = 32; m > 0; m >>= 1) s += __shfl_xor(s, m, 64);
  const float mu = s * (1.f / 256.f);
  const float dx = v.x - mu, dy = v.y - mu, dz = v.z - mu, dw = v.w - mu;
  float q = dx*dx + dy*dy + dz*dz + dw*dw;
  #pragma unroll
  for (int m = 32; m > 0; m >>= 1) q += __shfl_xor(q, m, 64);
  const float rstd = rsqrtf(q * (1.f / 256.f) + 1e-5f);

  __shared__ float ln[256];
  const int i4 = lane * 4;
  ln[i4 + 0] = dx * rstd * lng[i4 + 0] + lnb[i4 + 0];
  ln[i4 + 1] = dy * rstd * lng[i4 + 1] + lnb[i4 + 1];
  ln[i4 + 2] = dz * rstd * lng[i4 + 2] + lnb[i4 + 2];
  ln[i4 + 3] = dw * rstd * lng[i4 + 3] + lnb[i4 + 3];
  __syncthreads();

  float hd = 0.f;
  if (lane < 32) {
    const float* w = W1 + (size_t)lane * H_;
    float a = 0.f;
    for (int k = 0; k < H_; ++k) a += ln[k] * w[k];
    a += b1[lane];
    hd = fmaxf(a, 0.f) * W2[lane];
  }
  #pragma unroll
  for (int m = 16; m > 0; m >>= 1) hd += __shfl_xor(hd, m, 64);
  if (lane == 0) out[b] = hd + b2[0];
}

// ---------------------------------------------------------------------------
extern "C" void kernel_launch(void* const* d_in, const int* in_sizes, int n_in,
                              void* d_out, int out_size, void* d_ws, size_t ws_size,
                              hipStream_t stream)
{
  const float* x     = (const float*)d_in[0];
  const float* W_ih0 = (const float*)d_in[1];
  const float* W_ihr = (const float*)d_in[2];
  const float* W_hh  = (const float*)d_in[3];
  const float* b_ih  = (const float*)d_in[4];
  const float* b_hh  = (const float*)d_in[5];
  const float* lng   = (const float*)d_in[6];
  const float* lnb   = (const float*)d_in[7];
  const float* W1    = (const float*)d_in[8];
  const float* b1    = (const float*)d_in[9];
  const float* W2    = (const float*)d_in[10];
  const float* b2    = (const float*)d_in[11];
  float* out = (float*)d_out;

  const size_t ybf_elems  = (size_t)B_ * S_ * H_;
  const size_t wihp_elems = 49152 + 2 * 196608;
  const size_t h_elems    = (size_t)B_ * H_;
  const size_t whp_elems  = (size_t)G3_ * H_;

  int CH = 16;                         // 192 tiles/chunk <= 208 workers
  while (CH > 8) {
    size_t need = ybf_elems * 2 + wihp_elems * 2
                + 6 * (size_t)B_ * CH * G3_ * 2
                + (3 * h_elems + 3 * 768) * 4
                + 3 * whp_elems * 2 + 8192;
    if (need <= ws_size) break;
    CH >>= 1;
  }
  const int chsh = __builtin_ctz((unsigned)CH);
  const size_t gx_elems = (size_t)B_ * CH * G3_;
  const int cpl = S_ / CH;

  unsigned short* ybf    = (unsigned short*)d_ws;
  unsigned short* wihp   = ybf + ybf_elems;
  unsigned short* gxbase = wihp + wihp_elems;
  float* hbuf = (float*)(gxbase + 6 * gx_elems);
  unsigned short* Whp = (unsigned short*)(hbuf + 3 * h_elems);
  float* bias2 = (float*)(Whp + 3 * whp_elems);
  unsigned* gemm_done = (unsigned*)(bias2 + 3 * 768);
  unsigned* scan_done = gemm_done + 3 * cpl;

  const size_t lds_bytes = 131072 + 16384;   // 144 KiB

  hipMemsetAsync(gemm_done, 0, 2 * 3 * (size_t)cpl * sizeof(unsigned), stream);

  pack_bf16<<<(49152 / 8 + 255) / 256, 256, 0, stream>>>(W_ih0, wihp, 49152 / 8);
  pack_bf16<<<(393216 / 8 + 255) / 256, 256, 0, stream>>>(
      W_ihr, wihp + 49152, 393216 / 8);
  for (int l = 0; l < 3; ++l) {
    pack_whh<<<dim3(48, 8), 64, 0, stream>>>(
        W_hh + (size_t)l * G3_ * H_, Whp + (size_t)l * whp_elems,
        b_ih + (size_t)l * G3_, b_hh + (size_t)l * G3_, bias2 + l * 768);
  }

  {
    int CHa = CH, chsha = chsh, cpla = cpl;
    const float* xa = x;
    unsigned short* ybfa = ybf;
    const unsigned short* wihpa = wihp;
    const unsigned short* Whpa = Whp;
    const float* bhha = b_hh;
    const float* bias2a = bias2;
    unsigned short* gxa = gxbase;
    float* hbufa = hbuf;
    unsigned* gda = gemm_done;
    unsigned* sda = scan_done;
    void* args[] = { &CHa, &chsha, &cpla, &xa, &ybfa, &wihpa, &Whpa, &bhha,
                     &bias2a, &gxa, &hbufa, &gda, &sda };
    hipLaunchCooperativeKernel((void*)persist_k, dim3(256), dim3(1024),
                               args, (unsigned)lds_bytes, stream);
  }

  head_kernel<<<256, 64, 0, stream>>>(hbuf + 2 * h_elems, lng, lnb,
                                      W1, b1, W2, b2, out);
}

// Round 21
// 1413.330 us; speedup vs baseline: 1.7600x; 1.7600x over previous
//
#include <hip/hip_runtime.h>
#include <stdint.h>

#define B_  256
#define S_  512
#define D_  64
#define H_  256
#define G3_ 768

typedef __attribute__((ext_vector_type(8))) short s8v;   // 8 bf16 (4 VGPRs)
typedef __attribute__((ext_vector_type(4))) short s4v;   // 4 bf16 (2 VGPRs)
typedef __attribute__((ext_vector_type(4))) float f4v;   // MFMA accumulator
typedef __attribute__((ext_vector_type(4))) float f4r;   // raw float4

#define MF(a, b, c) __builtin_amdgcn_mfma_f32_16x16x32_bf16((a), (b), (c), 0, 0, 0)

__device__ __forceinline__ unsigned short f2bf(float x) {  // RNE
  unsigned u = __float_as_uint(x);
  unsigned r = (u + 0x7fffu + ((u >> 16) & 1u)) >> 16;
  return (unsigned short)r;
}
__device__ __forceinline__ float bf2f(unsigned short s) {
  return __uint_as_float(((unsigned)s) << 16);
}
__device__ __forceinline__ float sigm(float x) {
  return __builtin_amdgcn_rcpf(1.f + __expf(-x));
}
__device__ __forceinline__ float tanh_f(float x) {
  return 1.f - 2.f * __builtin_amdgcn_rcpf(1.f + __expf(2.f * x));
}

// ---------------------------------------------------------------------------
// Generic fp32 -> bf16 pack (8 elements/thread).
// ---------------------------------------------------------------------------
__global__ __launch_bounds__(256) void pack_bf16(
    const float* __restrict__ src, unsigned short* __restrict__ dst, int n8)
{
  const int i = blockIdx.x * 256 + threadIdx.x;
  if (i >= n8) return;
  const float4 f0 = *(const float4*)(src + (size_t)i * 8);
  const float4 f1 = *(const float4*)(src + (size_t)i * 8 + 4);
  unsigned short h[8] = { f2bf(f0.x), f2bf(f0.y), f2bf(f0.z), f2bf(f0.w),
                          f2bf(f1.x), f2bf(f1.y), f2bf(f1.z), f2bf(f1.w) };
  *(s8v*)&dst[(size_t)i * 8] = *(s8v*)h;
}

// ---------------------------------------------------------------------------
// Pack W_hh into MFMA fragment order (bf16-hi) + fold biases (block 0,0).
// ---------------------------------------------------------------------------
__global__ __launch_bounds__(64) void pack_whh(
    const float* __restrict__ Whh, unsigned short* __restrict__ Whp,
    const float* __restrict__ bih, const float* __restrict__ bhh,
    float* __restrict__ bias2)
{
  const int gti = blockIdx.x, kc = blockIdx.y, lane = threadIdx.x;
  const int rowp = gti * 16 + (lane & 15);
  const int k0  = kc * 32 + (lane >> 4) * 8;
  const float* src = &Whh[(size_t)rowp * H_ + k0];
  unsigned short hi8[8];
  #pragma unroll
  for (int s = 0; s < 8; ++s) hi8[s] = f2bf(src[s]);
  const size_t o = ((size_t)(gti * 8 + kc) * 64 + lane) * 8;
  *(s8v*)&Whp[o] = *(s8v*)hi8;

  if (gti == 0 && kc == 0) {
    #pragma unroll
    for (int i = 0; i < 12; ++i) {
      int g = i * 64 + lane;
      bias2[g] = bih[g] + (g < 512 ? bhh[g] : 0.f);
    }
  }
}

// ---------------------------------------------------------------------------
// Layer-pipelined fused dispatch for slot s (R17 structure, bf16 IO).
//   Blocks [0,48): scan role — block b runs scan(l=b/16, chunk c=s-2l).
//   Blocks [48,...): gemm role (LDS-staged datapath, bf16 in/out),
//     slice l computes gemm(l, c2=s+1-2l) into bf16 gx[l][c2&1].
// Ordering via dispatch boundaries only (chain verified in R17).
// ---------------------------------------------------------------------------
__global__ __launch_bounds__(1024, 4) void fused_step(
    int s, int CH, int chsh, int cpl,
    const float* __restrict__ x, unsigned short* __restrict__ ybf,
    const unsigned short* __restrict__ wihp,
    const unsigned short* __restrict__ Whp, const float* __restrict__ bhh_all,
    const float* __restrict__ bias2, unsigned short* __restrict__ gxbase,
    float* __restrict__ hbuf)
{
  const int tid = threadIdx.x;
  const int wid = tid >> 6, lane = tid & 63;
  const int fr = lane & 15, fq = lane >> 4;
  const size_t gx_elems = (size_t)B_ * CH * G3_;

  extern __shared__ unsigned short lds_[];

  if (blockIdx.x < 48) {
    // ===================== SCAN ROLE =======================================
    const int l = blockIdx.x >> 4;
    const int c = s - 2 * l;
    if (c < 0 || c >= cpl) return;

    const unsigned short* Whp_s = Whp + (size_t)l * G3_ * H_;
    const float* bhh_s = bhh_all + (size_t)l * G3_;
    float* hb = hbuf + (size_t)l * B_ * H_;
    const unsigned short* gx_r = gxbase + (size_t)(2 * l + (c & 1)) * gx_elems;
    const int t0s = c * CH;
    const int lastL = (l == 2) ? 1 : 0;

    unsigned short* WhN  = lds_;                 // [16 w][8 kc][512] = 128KB
    unsigned short* Abuf = lds_ + 65536;         // [2][8 kc][512] = 16KB

    const int bid = blockIdx.x & 15;
    const int b0  = bid * 16;
    const int bb  = fr;

    const s8v* WhpV = (const s8v*)Whp_s;

    s8v whr[8], whz[8];
    #pragma unroll
    for (int kc = 0; kc < 8; ++kc) {
      whr[kc] = WhpV[((     wid) * 8 + kc) * 64 + lane];
      whz[kc] = WhpV[((16 + wid) * 8 + kc) * 64 + lane];
    }
    #pragma unroll
    for (int kc = 0; kc < 8; ++kc) {
      s8v v = WhpV[((32 + wid) * 8 + kc) * 64 + lane];
      *(s8v*)&WhN[(wid * 8 + kc) * 512 + lane * 8] = v;
    }

    const int u0 = 16 * wid + 4 * fq;
    const f4r bhn4 = *(const f4r*)&bhh_s[2 * H_ + u0];

    f4r hn4 = {0.f, 0.f, 0.f, 0.f};
    if (t0s != 0) hn4 = *(const f4r*)&hb[(size_t)(b0 + bb) * H_ + u0];

    const int kcw  = wid >> 1;
    const int lp   = bb | (((2 * wid + (fq >> 1)) & 3) << 4);
    const int eo   = (fq & 1) * 4;
    const int aoff = kcw * 512 + lp * 8 + eo;

    {
      s4v hh;
      #pragma unroll
      for (int j = 0; j < 4; ++j) hh[j] = (short)f2bf(hn4[j]);
      *(s4v*)&Abuf[aoff] = hh;
    }

    // preload gx(t=0), bf16
    const unsigned short* gb0 = gx_r + ((size_t)(b0 + bb) * CH) * G3_;
    s4v xr4 = *(const s4v*)(gb0 + u0);
    s4v xz4 = *(const s4v*)(gb0 + H_ + u0);
    s4v xn4 = *(const s4v*)(gb0 + 2 * H_ + u0);

    int cur = 0;
    for (int t = 0; t < CH; ++t) {
      __syncthreads();   // Abuf[cur] (and WhN at t=0) visible

      // prefetch gx(t+1)
      const int tn = (t + 1 < CH) ? t + 1 : t;
      const unsigned short* gbn = gx_r + ((size_t)(b0 + bb) * CH + tn) * G3_;
      s4v xr_n = *(const s4v*)(gbn + u0);
      s4v xz_n = *(const s4v*)(gbn + H_ + u0);
      s4v xn_n = *(const s4v*)(gbn + 2 * H_ + u0);

      f4v accR = {}, accZ = {}, accN = {};
      #pragma unroll
      for (int kc = 0; kc < 8; ++kc) {
        s8v ahh = *(const s8v*)&Abuf[cur * 4096 + kc * 512 + lane * 8];
        s8v wn  = *(const s8v*)&WhN[(wid * 8 + kc) * 512 + lane * 8];
        accR = MF(whr[kc], ahh, accR);
        accZ = MF(whz[kc], ahh, accZ);
        accN = MF(wn,      ahh, accN);
      }

      #pragma unroll
      for (int i = 0; i < 4; ++i) {
        const float r = sigm(bf2f((unsigned short)xr4[i]) + accR[i]);
        const float z = sigm(bf2f((unsigned short)xz4[i]) + accZ[i]);
        const float n = tanh_f(bf2f((unsigned short)xn4[i]) + r * (accN[i] + bhn4[i]));
        hn4[i] = (1.f - z) * n + z * hn4[i];
      }
      s4v hh;
      #pragma unroll
      for (int j = 0; j < 4; ++j) hh[j] = (short)f2bf(hn4[j]);
      if (!lastL) {
        __builtin_nontemporal_store(
            hh, (s4v*)&ybf[((size_t)(b0 + bb) * S_ + (t0s + t)) * H_ + u0]);
      }
      *(s4v*)&Abuf[(cur ^ 1) * 4096 + aoff] = hh;
      xr4 = xr_n; xz4 = xz_n; xn4 = xn_n;
      cur ^= 1;
    }

    *(f4r*)&hb[(size_t)(b0 + bb) * H_ + u0] = hn4;

  } else {
    // ===================== GEMM ROLE (LDS-staged, bf16 in/out) =============
    const int g = blockIdx.x - 48;
    const int per = CH * 12;
    const int l = g / per;
    if (l >= 3) return;
    const int c2 = s + 1 - 2 * l;
    if (c2 < 0 || c2 >= cpl) return;

    const int gidx  = g % per;
    const int mtile = gidx / 12, gtile = gidx % 12;
    const int r0 = mtile * 256, g0 = gtile * 64;

    const int    K   = (l == 0) ? D_ : H_;
    const unsigned short* Wp =
        (l == 0) ? wihp : (wihp + 49152 + (size_t)(l - 1) * 196608);
    const float* b2g = bias2 + l * 768;
    unsigned short* gx_w = gxbase + (size_t)(2 * l + (c2 & 1)) * gx_elems;
    const int t0g = c2 * CH;

    unsigned short* Ah  = lds_;            // [256][40] = 20480 B
    unsigned short* Wh  = lds_ + 10240;    // [64][40]  = 5120 B
    unsigned short* gxs = lds_ + 12800;    // [256][64] = 32768 B (epilogue)

    const int row = tid >> 2;              // 0..255
    const int ks  = (tid & 3) * 8;
    const int r = r0 + row;
    const int rg = ((r >> chsh) * S_) + t0g + (r & (CH - 1));

    f4v acc[4] = {};

    for (int k0 = 0; k0 < K; k0 += 32) {
      s8v aval;
      if (l == 0) {
        const float* apf = x + (size_t)rg * D_ + k0 + ks;
        float4 f0 = *(const float4*)(apf);
        float4 f1 = *(const float4*)(apf + 4);
        unsigned short a8[8] = { f2bf(f0.x), f2bf(f0.y), f2bf(f0.z), f2bf(f0.w),
                                 f2bf(f1.x), f2bf(f1.y), f2bf(f1.z), f2bf(f1.w) };
        aval = *(s8v*)a8;
      } else {
        aval = *(const s8v*)(ybf + (size_t)rg * H_ + k0 + ks);
      }
      s8v wval;
      if (tid < 256)
        wval = *(const s8v*)(Wp + (size_t)(g0 + row) * K + k0 + ks);
      __syncthreads();   // prev frag reads done
      *(s8v*)&Ah[row * 40 + ks] = aval;
      if (tid < 256) *(s8v*)&Wh[row * 40 + ks] = wval;
      __syncthreads();

      s8v a_hi = *(const s8v*)&Ah[(16 * wid + fr) * 40 + fq * 8];
      #pragma unroll
      for (int c = 0; c < 4; ++c) {
        s8v b_hi = *(const s8v*)&Wh[(c * 16 + fr) * 40 + fq * 8];
        acc[c] = MF(a_hi, b_hi, acc[c]);
      }
    }

    // epilogue: bf16 results -> LDS bounce -> coalesced global stores
    #pragma unroll
    for (int c = 0; c < 4; ++c) {
      const float bi = b2g[g0 + c * 16 + fr];
      #pragma unroll
      for (int i = 0; i < 4; ++i)
        gxs[(wid * 16 + fq * 4 + i) * 64 + c * 16 + fr] = f2bf(acc[c][i] + bi);
    }
    __syncthreads();
    {
      const int srow = tid >> 2, soff = (tid & 3) * 16;
      s8v v0 = *(const s8v*)&gxs[srow * 64 + soff];
      s8v v1 = *(const s8v*)&gxs[srow * 64 + soff + 8];
      unsigned short* gp = gx_w + (size_t)(r0 + srow) * G3_ + g0 + soff;
      *(s8v*)gp = v0;
      *(s8v*)(gp + 8) = v1;
    }
  }
}

// ---------------------------------------------------------------------------
// Head: LayerNorm(h_last) -> MLP 256->32 (ReLU) -> 32->1. One wave per batch.
// ---------------------------------------------------------------------------
__global__ __launch_bounds__(64) void head_kernel(
    const float* __restrict__ hlast, const float* __restrict__ lng,
    const float* __restrict__ lnb, const float* __restrict__ W1,
    const float* __restrict__ b1, const float* __restrict__ W2,
    const float* __restrict__ b2, float* __restrict__ out)
{
  const int b = blockIdx.x;
  const int lane = threadIdx.x;
  float4 v = *(const float4*)&hlast[(size_t)b * H_ + lane * 4];
  float s = v.x + v.y + v.z + v.w;
  #pragma unroll
  for (int m = 32; m > 0; m >>= 1) s += __shfl_xor(s, m, 64);
  const float mu = s * (1.f / 256.f);
  const float dx = v.x - mu, dy = v.y - mu, dz = v.z - mu, dw = v.w - mu;
  float q = dx*dx + dy*dy + dz*dz + dw*dw;
  #pragma unroll
  for (int m = 32; m > 0; m >>= 1) q += __shfl_xor(q, m, 64);
  const float rstd = rsqrtf(q * (1.f / 256.f) + 1e-5f);

  __shared__ float ln[256];
  const int i4 = lane * 4;
  ln[i4 + 0] = dx * rstd * lng[i4 + 0] + lnb[i4 + 0];
  ln[i4 + 1] = dy * rstd * lng[i4 + 1] + lnb[i4 + 1];
  ln[i4 + 2] = dz * rstd * lng[i4 + 2] + lnb[i4 + 2];
  ln[i4 + 3] = dw * rstd * lng[i4 + 3] + lnb[i4 + 3];
  __syncthreads();

  float hd = 0.f;
  if (lane < 32) {
    const float* w = W1 + (size_t)lane * H_;
    float a = 0.f;
    for (int k = 0; k < H_; ++k) a += ln[k] * w[k];
    a += b1[lane];
    hd = fmaxf(a, 0.f) * W2[lane];
  }
  #pragma unroll
  for (int m = 16; m > 0; m >>= 1) hd += __shfl_xor(hd, m, 64);
  if (lane == 0) out[b] = hd + b2[0];
}

// ---------------------------------------------------------------------------
extern "C" void kernel_launch(void* const* d_in, const int* in_sizes, int n_in,
                              void* d_out, int out_size, void* d_ws, size_t ws_size,
                              hipStream_t stream)
{
  const float* x     = (const float*)d_in[0];
  const float* W_ih0 = (const float*)d_in[1];
  const float* W_ihr = (const float*)d_in[2];
  const float* W_hh  = (const float*)d_in[3];
  const float* b_ih  = (const float*)d_in[4];
  const float* b_hh  = (const float*)d_in[5];
  const float* lng   = (const float*)d_in[6];
  const float* lnb   = (const float*)d_in[7];
  const float* W1    = (const float*)d_in[8];
  const float* b1    = (const float*)d_in[9];
  const float* W2    = (const float*)d_in[10];
  const float* b2    = (const float*)d_in[11];
  float* out = (float*)d_out;

  const size_t ybf_elems  = (size_t)B_ * S_ * H_;      // 33.5M ushorts (67MB)
  const size_t wihp_elems = 49152 + 2 * 196608;
  const size_t h_elems    = (size_t)B_ * H_;
  const size_t whp_elems  = (size_t)G3_ * H_;

  // CH = 32: measured balance point (scan ~48us >= gemm ~5.5 rounds hidden)
  int CH = 32;
  while (CH > 8) {
    size_t need = ybf_elems * 2 + wihp_elems * 2
                + 6 * (size_t)B_ * CH * G3_ * 2
                + (3 * h_elems + 3 * 768) * 4
                + 3 * whp_elems * 2 + 8192;
    if (need <= ws_size) break;
    CH >>= 1;
  }
  const int chsh = __builtin_ctz((unsigned)CH);
  const size_t gx_elems = (size_t)B_ * CH * G3_;
  const int cpl = S_ / CH;

  unsigned short* ybf    = (unsigned short*)d_ws;
  unsigned short* wihp   = ybf + ybf_elems;
  unsigned short* gxbase = wihp + wihp_elems;
  float* hbuf = (float*)(gxbase + 6 * gx_elems);
  unsigned short* Whp = (unsigned short*)(hbuf + 3 * h_elems);
  float* bias2 = (float*)(Whp + 3 * whp_elems);

  const size_t lds_bytes = 131072 + 16384;   // 144 KiB
  const int grid = 48 + 3 * CH * 12;

  pack_bf16<<<(49152 / 8 + 255) / 256, 256, 0, stream>>>(W_ih0, wihp, 49152 / 8);
  pack_bf16<<<(393216 / 8 + 255) / 256, 256, 0, stream>>>(
      W_ihr, wihp + 49152, 393216 / 8);
  for (int l = 0; l < 3; ++l) {
    pack_whh<<<dim3(48, 8), 64, 0, stream>>>(
        W_hh + (size_t)l * G3_ * H_, Whp + (size_t)l * whp_elems,
        b_ih + (size_t)l * G3_, b_hh + (size_t)l * G3_, bias2 + l * 768);
  }

  for (int s = -1; s <= cpl + 3; ++s) {
    fused_step<<<grid, 1024, lds_bytes, stream>>>(
        s, CH, chsh, cpl, x, ybf, wihp, Whp, b_hh, bias2, gxbase, hbuf);
  }

  head_kernel<<<256, 64, 0, stream>>>(hbuf + 2 * h_elems, lng, lnb,
                                      W1, b1, W2, b2, out);
}